// Round 1
// 137.821 us; speedup vs baseline: 1.0852x; 1.0852x over previous
//
#include <hip/hip_runtime.h>

#define MARGIN 0.85f

__device__ __forceinline__ float gelu_exact(float x) {
    return 0.5f * x * (1.0f + erff(x * 0.7071067811865475f));
}

// One block per b. Phase 1: 256 threads gelu the 62 Householder vectors
// (head rows 0..30, tail rows 31..61) into LDS + per-row 2/||w||^2.
// Phase 2: wave 0 applies the reflections as VECTOR ops (never building Q):
//   head:  x <- x H0 H1 ... H30   (i = 0..30)   [x_rot = x @ Q]
//   tail:  w <- H0 (H1 (... (H30 y)))  (i = 30..0)  [w_sp = Q y_sp]
// with boosts exactly as the reference (same eps terms). Identity (unchanged
// from the previously passing kernel): score = const_b + w.t - (sum t^2 - 2 t0^2)
// + tanh(bias_tail), const_b = MARGIN - th^T G th + tanh(bias_head).
// Phase 3: all 256 threads score; their emb gathers were issued at kernel
// entry so the latency hides under phases 1-2.
__global__ __launch_bounds__(256) void fused_kernel(
    const int* __restrict__ u_idx, const int* __restrict__ r_idx,
    const int* __restrict__ v_idx,
    const float* __restrict__ emb,
    const float* __restrict__ bias_head, const float* __restrict__ bias_tail,
    const float* __restrict__ head_rot_w, const float* __restrict__ head_boost_w,
    const float* __restrict__ tail_rot_w, const float* __restrict__ tail_boost_w,
    float* __restrict__ out)
{
    __shared__ float wrow[62][33];   // pitch 33 floats: conflict-free row AND column access
    __shared__ float inv2n[62];
    __shared__ float hsld[32];
    __shared__ __align__(16) float wl[36];

    const int tid = threadIdx.x;
    const int b = blockIdx.x;
    const int r  = __builtin_amdgcn_readfirstlane(r_idx[b]);
    const int ub = __builtin_amdgcn_readfirstlane(u_idx[b]);

    // ---- issue score-phase gathers early; consumed after the last barrier ----
    const int vi = v_idx[(size_t)b * 256 + tid];
    const float4* ep = reinterpret_cast<const float4*>(emb + (size_t)vi * 32);
    const float4 e0 = ep[0], e1 = ep[1], e2 = ep[2], e3 = ep[3],
                 e4 = ep[4], e5 = ep[5], e6 = ep[6], e7 = ep[7];
    const float tb = tanhf(bias_tail[vi]);

    // ---- phase 1: gelu rotation weights into LDS ----
    const float* hw = head_rot_w + (size_t)r * 961;
    const float* tw = tail_rot_w + (size_t)r * 961;
    for (int e = tid; e < 961; e += 256) {
        const int row = e / 31;
        const int col = e - row * 31;
        wrow[row][col]      = gelu_exact(hw[e]);
        wrow[31 + row][col] = gelu_exact(tw[e]);
    }
    if (tid < 62) wrow[tid][31] = 0.0f;   // lane 31 reads contribute 0
    if (tid < 32) hsld[tid] = emb[(size_t)ub * 32 + tid];
    __syncthreads();

    // ---- per-row inverse norms (column access: pitch 33 -> conflict-free) ----
    if (tid < 62) {
        float n = 0.0f;
        #pragma unroll
        for (int k = 0; k < 31; ++k) n = fmaf(wrow[tid][k], wrow[tid][k], n);
        inv2n[tid] = 2.0f / n;
    }
    __syncthreads();

    // ---- phase 2: wave 0, lane k = component k (lanes 32-63 mirror harmlessly) ----
    if (tid < 64) {
        const int k = tid & 31;
        const bool act = (k < 31);

        // head rotation: x <- x H0 H1 ... H30
        float x = act ? hsld[1 + k] : 0.0f;
        const float h0 = hsld[0];
        #pragma unroll
        for (int i = 0; i < 31; ++i) {
            const float w = wrow[i][k];
            float p = x * w;
            p += __shfl_xor(p, 1);
            p += __shfl_xor(p, 2);
            p += __shfl_xor(p, 4);
            p += __shfl_xor(p, 8);
            p += __shfl_xor(p, 16);
            x = fmaf(-(p * inv2n[i]), w, x);
        }

        // head boost (reference formulas, same eps)
        const float roh = act ? tanhf(head_boost_w[(size_t)r * 31 + k]) * 0.03125f : 0.0f;
        float pv = roh * roh;     // -> v2
        float pd = x * roh;       // -> dot
        #pragma unroll
        for (int m = 1; m < 32; m <<= 1) {
            pv += __shfl_xor(pv, m);
            pd += __shfl_xor(pd, m);
        }
        const float zh = 1.0f / (sqrtf(1.0f - pv) + 1e-8f);
        const float ch = (zh - 1.0f) / (pv + 1e-9f);
        const float th  = fmaf(roh, ch * pd - zh * h0, x);   // spatial component k
        const float th0 = zh * (h0 - pd);

        // y = 2 * B_tail * (G th)
        const float rot = act ? tanhf(tail_boost_w[(size_t)r * 31 + k]) * 0.03125f : 0.0f;
        float qv = rot * rot;     // -> v2_tail
        float qd = rot * th;      // -> dot(th_sp, rot)
        float qb = th * th;       // -> beta spatial part
        #pragma unroll
        for (int m = 1; m < 32; m <<= 1) {
            qv += __shfl_xor(qv, m);
            qd += __shfl_xor(qd, m);
            qb += __shfl_xor(qb, m);
        }
        const float zt = 1.0f / (sqrtf(1.0f - qv) + 1e-8f);
        const float ct = (zt - 1.0f) / (qv + 1e-9f);
        float y = 2.0f * fmaf(fmaf(zt, th0, ct * qd), rot, th);
        const float y0 = 2.0f * zt * (-th0 - qd);

        // tail rotation: w_sp = H0 (H1 (... (H30 y_sp)))  -> reverse order
        #pragma unroll
        for (int i = 30; i >= 0; --i) {
            const float w = wrow[31 + i][k];
            float p = y * w;
            p += __shfl_xor(p, 1);
            p += __shfl_xor(p, 2);
            p += __shfl_xor(p, 4);
            p += __shfl_xor(p, 8);
            p += __shfl_xor(p, 16);
            y = fmaf(-(p * inv2n[31 + i]), w, y);
        }

        if (tid < 32) {
            if (act) wl[1 + k] = y;
            else     wl[0] = y0;            // lane 31
        }
        if (tid == 0) {
            const float beta = qb - th0 * th0;
            wl[32] = MARGIN - beta + tanhf(bias_head[ub]);
        }
    }
    __syncthreads();

    // ---- phase 3: score from pre-fetched registers ----
    float dotw = 0.0f, qsum = 0.0f;
    const float t0 = e0.x;
#define ACC(EV, WI)                                                       \
    {                                                                     \
        const float4 wq = *reinterpret_cast<const float4*>(&wl[4 * WI]);  \
        dotw = fmaf(EV.x, wq.x, dotw); dotw = fmaf(EV.y, wq.y, dotw);     \
        dotw = fmaf(EV.z, wq.z, dotw); dotw = fmaf(EV.w, wq.w, dotw);     \
        qsum = fmaf(EV.x, EV.x, qsum); qsum = fmaf(EV.y, EV.y, qsum);     \
        qsum = fmaf(EV.z, EV.z, qsum); qsum = fmaf(EV.w, EV.w, qsum);     \
    }
    ACC(e0, 0) ACC(e1, 1) ACC(e2, 2) ACC(e3, 3)
    ACC(e4, 4) ACC(e5, 5) ACC(e6, 6) ACC(e7, 7)
#undef ACC

    out[(size_t)b * 256 + tid] = wl[32] + dotw - qsum + 2.0f * t0 * t0 + tb;
}

extern "C" void kernel_launch(void* const* d_in, const int* in_sizes, int n_in,
                              void* d_out, int out_size, void* d_ws, size_t ws_size,
                              hipStream_t stream) {
    (void)n_in; (void)out_size; (void)d_ws; (void)ws_size;
    const int B = in_sizes[0];   // 1024
    fused_kernel<<<B, 256, 0, stream>>>(
        (const int*)d_in[0], (const int*)d_in[1], (const int*)d_in[2],
        (const float*)d_in[3], (const float*)d_in[4], (const float*)d_in[5],
        (const float*)d_in[6], (const float*)d_in[7],
        (const float*)d_in[8], (const float*)d_in[9],
        (float*)d_out);
}

// Round 2
// 133.921 us; speedup vs baseline: 1.1168x; 1.0291x over previous
//
#include <hip/hip_runtime.h>

#define MARGIN 0.85f

__device__ __forceinline__ float gelu_exact(float x) {
    return 0.5f * x * (1.0f + erff(x * 0.7071067811865475f));
}

// One block per b.
// Phase 1: 256 threads gelu the 62 Householder vectors into LDS (+ hsld).
// Phase 1b: per-row 2/||w||^2.
// >>> gather issue point: emb rows + bias_tail are issued HERE (after the
//     last pre-chain barrier) so they stay in flight across the chain —
//     the compiler drains vmcnt(0) at every s_barrier, so issuing them at
//     kernel entry (round 1) serialized all 33 MB of emb traffic BEFORE
//     the serial chain. Now waves 1-3 issue and wait at the final barrier
//     while wave 0 runs the chain; HBM streams underneath it.
// Phase 2 (wave 0 only): head chain x<-xH0..H30, boosts (exact ref eps),
//     tail chain w=H0(..(H30 y)), write wl[34].
// Phase 3: score from the pre-fetched registers.
__global__ __launch_bounds__(256) void fused_kernel(
    const int* __restrict__ u_idx, const int* __restrict__ r_idx,
    const int* __restrict__ v_idx,
    const float* __restrict__ emb,
    const float* __restrict__ bias_head, const float* __restrict__ bias_tail,
    const float* __restrict__ head_rot_w, const float* __restrict__ head_boost_w,
    const float* __restrict__ tail_rot_w, const float* __restrict__ tail_boost_w,
    float* __restrict__ out)
{
    __shared__ float wrow[62][33];   // pitch 33: conflict-free row AND column access
    __shared__ float inv2n[62];
    __shared__ float hsld[32];
    __shared__ __align__(16) float wl[36];

    const int tid = threadIdx.x;
    const int b = blockIdx.x;
    const int r  = __builtin_amdgcn_readfirstlane(r_idx[b]);
    const int ub = __builtin_amdgcn_readfirstlane(u_idx[b]);

    // small early load: tail index (needed to form gather addresses later)
    const int vi = v_idx[(size_t)b * 256 + tid];

    // ---- phase 1: gelu rotation weights into LDS ----
    const float* hw = head_rot_w + (size_t)r * 961;
    const float* tw = tail_rot_w + (size_t)r * 961;
    for (int e = tid; e < 961; e += 256) {
        const int row = e / 31;
        const int col = e - row * 31;
        wrow[row][col]      = gelu_exact(hw[e]);
        wrow[31 + row][col] = gelu_exact(tw[e]);
    }
    if (tid < 62) wrow[tid][31] = 0.0f;   // lane-31 reads contribute 0
    if (tid < 32) hsld[tid] = emb[(size_t)ub * 32 + tid];
    __syncthreads();

    // ---- phase 1b: per-row inverse norms (column access, conflict-free) ----
    if (tid < 62) {
        float n = 0.0f;
        #pragma unroll
        for (int k = 0; k < 31; ++k) n = fmaf(wrow[tid][k], wrow[tid][k], n);
        inv2n[tid] = 2.0f / n;
    }
    __syncthreads();

    // ---- gather issue point: in flight across the chain, drained at the
    //      final barrier ----
    const float4* ep = reinterpret_cast<const float4*>(emb + (size_t)vi * 32);
    const float4 e0 = ep[0], e1 = ep[1], e2 = ep[2], e3 = ep[3],
                 e4 = ep[4], e5 = ep[5], e6 = ep[6], e7 = ep[7];
    const float btl = bias_tail[vi];

    // ---- phase 2: wave 0, lane k = component k (lanes 32-63 mirror) ----
    if (tid < 64) {
        const int k = tid & 31;
        const bool act = (k < 31);

        // head rotation: x <- x H0 H1 ... H30
        float x = act ? hsld[1 + k] : 0.0f;
        const float h0 = hsld[0];
        #pragma unroll
        for (int i = 0; i < 31; ++i) {
            const float w = wrow[i][k];
            float p = x * w;
            p += __shfl_xor(p, 1);
            p += __shfl_xor(p, 2);
            p += __shfl_xor(p, 4);
            p += __shfl_xor(p, 8);
            p += __shfl_xor(p, 16);
            x = fmaf(-(p * inv2n[i]), w, x);
        }

        // head boost (reference formulas, same eps)
        const float roh = act ? tanhf(head_boost_w[(size_t)r * 31 + k]) * 0.03125f : 0.0f;
        float pv = roh * roh;     // -> v2
        float pd = x * roh;       // -> dot
        #pragma unroll
        for (int m = 1; m < 32; m <<= 1) {
            pv += __shfl_xor(pv, m);
            pd += __shfl_xor(pd, m);
        }
        const float zh = 1.0f / (sqrtf(1.0f - pv) + 1e-8f);
        const float ch = (zh - 1.0f) / (pv + 1e-9f);
        const float th  = fmaf(roh, ch * pd - zh * h0, x);   // spatial comp k
        const float th0 = zh * (h0 - pd);

        // y = 2 * B_tail * (G th)
        const float rot = act ? tanhf(tail_boost_w[(size_t)r * 31 + k]) * 0.03125f : 0.0f;
        float qv = rot * rot;     // -> v2_tail
        float qd = rot * th;      // -> dot(th_sp, rot)
        float qb = th * th;       // -> beta spatial part
        #pragma unroll
        for (int m = 1; m < 32; m <<= 1) {
            qv += __shfl_xor(qv, m);
            qd += __shfl_xor(qd, m);
            qb += __shfl_xor(qb, m);
        }
        const float zt = 1.0f / (sqrtf(1.0f - qv) + 1e-8f);
        const float ct = (zt - 1.0f) / (qv + 1e-9f);
        float y = 2.0f * fmaf(fmaf(zt, th0, ct * qd), rot, th);
        const float y0 = 2.0f * zt * (-th0 - qd);

        // tail rotation: w_sp = H0 (H1 (... (H30 y_sp)))  -> reverse order
        #pragma unroll
        for (int i = 30; i >= 0; --i) {
            const float w = wrow[31 + i][k];
            float p = y * w;
            p += __shfl_xor(p, 1);
            p += __shfl_xor(p, 2);
            p += __shfl_xor(p, 4);
            p += __shfl_xor(p, 8);
            p += __shfl_xor(p, 16);
            y = fmaf(-(p * inv2n[31 + i]), w, y);
        }

        if (tid < 32) {
            if (act) wl[1 + k] = y;
            else     wl[0] = y0;            // lane 31
        }
        if (tid == 0) {
            const float beta = qb - th0 * th0;
            wl[32] = MARGIN - beta + tanhf(bias_head[ub]);
        }
    }
    __syncthreads();   // drains the in-flight gathers too

    // ---- phase 3: score from pre-fetched registers ----
    float dotw = 0.0f, qsum = 0.0f;
    const float t0 = e0.x;
#define ACC(EV, WI)                                                       \
    {                                                                     \
        const float4 wq = *reinterpret_cast<const float4*>(&wl[4 * WI]);  \
        dotw = fmaf(EV.x, wq.x, dotw); dotw = fmaf(EV.y, wq.y, dotw);     \
        dotw = fmaf(EV.z, wq.z, dotw); dotw = fmaf(EV.w, wq.w, dotw);     \
        qsum = fmaf(EV.x, EV.x, qsum); qsum = fmaf(EV.y, EV.y, qsum);     \
        qsum = fmaf(EV.z, EV.z, qsum); qsum = fmaf(EV.w, EV.w, qsum);     \
    }
    ACC(e0, 0) ACC(e1, 1) ACC(e2, 2) ACC(e3, 3)
    ACC(e4, 4) ACC(e5, 5) ACC(e6, 6) ACC(e7, 7)
#undef ACC

    out[(size_t)b * 256 + tid] = wl[32] + dotw - qsum + 2.0f * t0 * t0 + tanhf(btl);
}

extern "C" void kernel_launch(void* const* d_in, const int* in_sizes, int n_in,
                              void* d_out, int out_size, void* d_ws, size_t ws_size,
                              hipStream_t stream) {
    (void)n_in; (void)out_size; (void)d_ws; (void)ws_size;
    const int B = in_sizes[0];   // 1024
    fused_kernel<<<B, 256, 0, stream>>>(
        (const int*)d_in[0], (const int*)d_in[1], (const int*)d_in[2],
        (const float*)d_in[3], (const float*)d_in[4], (const float*)d_in[5],
        (const float*)d_in[6], (const float*)d_in[7],
        (const float*)d_in[8], (const float*)d_in[9],
        (float*)d_out);
}

// Round 4
// 128.184 us; speedup vs baseline: 1.1668x; 1.0448x over previous
//
#include <hip/hip_runtime.h>

#define MARGIN 0.85f

__device__ __forceinline__ float gelu_exact(float x) {
    return 0.5f * x * (1.0f + erff(x * 0.7071067811865475f));
}

// sum over each 32-lane half, result broadcast to all lanes of the half.
// 4x DPP row_ror adds (VALU pipe, ~5cyc dependent) + 1 ds_swizzle xor16.
// Replaces 5 dependent ds_bpermute (__shfl_xor) ~250cyc with ~70cyc.
template<int CTRL>
__device__ __forceinline__ float dpp_add(float x) {
    return x + __int_as_float(__builtin_amdgcn_update_dpp(
        0, __float_as_int(x), CTRL, 0xF, 0xF, false));
}
__device__ __forceinline__ float reduce32(float x) {
    x = dpp_add<0x121>(x);   // row_ror:1  -> pairs
    x = dpp_add<0x122>(x);   // row_ror:2  -> 4s
    x = dpp_add<0x124>(x);   // row_ror:4  -> 8s
    x = dpp_add<0x128>(x);   // row_ror:8  -> row-of-16 sums
    x += __int_as_float(__builtin_amdgcn_ds_swizzle(__float_as_int(x), 0x401F)); // xor16
    return x;
}

// One block per b.
// Phase 1: 256 threads gelu 62 Householder vectors into LDS rows (head 0..30,
//   tail 32..62; rows 31 & 63 and column 31 are zero pads = identity refl.).
// Phase 1b: per-row 2/||w||^2 (0 for pads) + 96 cross-dots c_jk = w_j.w_k for
//   groups of 4 (threads 64..159, parallel, off the critical path).
// Gathers issued after the last pre-chain barrier (in flight across chain).
// Phase 2 (wave 0): grouped Householder chain — per group of 4 reflections,
//   ONE interleaved 4-dot reduction event + exact triangular recurrence using
//   the precomputed cross-dots (compact-WY, algebraically identical to the
//   sequential product). 16 reduction events instead of 62. Boosts = exact
//   reference formulas (same eps terms).
// Phase 3: score from pre-fetched registers.
__global__ __launch_bounds__(256) void fused_kernel(
    const int* __restrict__ u_idx, const int* __restrict__ r_idx,
    const int* __restrict__ v_idx,
    const float* __restrict__ emb,
    const float* __restrict__ bias_head, const float* __restrict__ bias_tail,
    const float* __restrict__ head_rot_w, const float* __restrict__ head_boost_w,
    const float* __restrict__ tail_rot_w, const float* __restrict__ tail_boost_w,
    float* __restrict__ out)
{
    __shared__ float wrow[64][33];   // pitch 33: conflict-free row AND column access
    __shared__ float inv2n[64];
    __shared__ float cd[2][8][6];    // cross-dots per (side, group, pair 01,02,03,12,13,23)
    __shared__ float hsld[32];
    __shared__ __align__(16) float wl[36];

    const int tid = threadIdx.x;
    const int b = blockIdx.x;
    const int r  = __builtin_amdgcn_readfirstlane(r_idx[b]);
    const int ub = __builtin_amdgcn_readfirstlane(u_idx[b]);

    // small early load: tail index (needed to form gather addresses later)
    const int vi = v_idx[(size_t)b * 256 + tid];

    // ---- phase 1: gelu rotation weights into LDS ----
    const float* hw = head_rot_w + (size_t)r * 961;
    const float* tw = tail_rot_w + (size_t)r * 961;
    for (int e = tid; e < 961; e += 256) {
        const int row = e / 31;
        const int col = e - row * 31;
        wrow[row][col]      = gelu_exact(hw[e]);
        wrow[32 + row][col] = gelu_exact(tw[e]);
    }
    if (tid < 64) wrow[tid][31] = 0.0f;                    // pad column
    if (tid >= 64 && tid < 97)   wrow[31][tid - 64] = 0.0f; // pad row (head side)
    if (tid >= 128 && tid < 161) wrow[63][tid - 128] = 0.0f;// pad row (tail side)
    if (tid < 32) hsld[tid] = emb[(size_t)ub * 32 + tid];
    __syncthreads();

    // ---- phase 1b: inverse norms + group cross-dots (parallel) ----
    if (tid < 64) {
        float n = 0.0f;
        #pragma unroll
        for (int k = 0; k < 31; ++k) n = fmaf(wrow[tid][k], wrow[tid][k], n);
        inv2n[tid] = ((tid & 31) == 31) ? 0.0f : 2.0f / n;  // pad rows: identity
    }
    if (tid >= 64 && tid < 160) {
        const int t = tid - 64;
        const int side = t / 48;
        const int rem = t % 48;
        const int g2 = rem / 6;
        const int pr = rem % 6;   // (0,1),(0,2),(0,3),(1,2),(1,3),(2,3)
        const int jj = (pr < 3) ? 0 : ((pr < 5) ? 1 : 2);
        const int kk = (pr < 3) ? (pr + 1) : ((pr < 5) ? (pr - 1) : 3);  // FIXED: pr-1 (was pr-2)
        const int ra = side * 32 + g2 * 4 + jj;
        const int rb = side * 32 + g2 * 4 + kk;
        float s = 0.0f;
        #pragma unroll
        for (int q = 0; q < 31; ++q) s = fmaf(wrow[ra][q], wrow[rb][q], s);
        cd[side][g2][pr] = s;
    }
    __syncthreads();

    // ---- gather issue point: in flight across the chain ----
    const float4* ep = reinterpret_cast<const float4*>(emb + (size_t)vi * 32);
    const float4 e0 = ep[0], e1 = ep[1], e2 = ep[2], e3 = ep[3],
                 e4 = ep[4], e5 = ep[5], e6 = ep[6], e7 = ep[7];
    const float btl = bias_tail[vi];

    // ---- phase 2: wave 0, lane k = component k (lanes 32-63 mirror) ----
    if (tid < 64) {
        const int k = tid & 31;
        const bool act = (k < 31);

        // boost vectors: load + tanh early (independent of the chain)
        const float roh = act ? tanhf(head_boost_w[(size_t)r * 31 + k]) * 0.03125f : 0.0f;
        const float rot = act ? tanhf(tail_boost_w[(size_t)r * 31 + k]) * 0.03125f : 0.0f;
        const float pv = reduce32(roh * roh);
        const float qv = reduce32(rot * rot);
        const float zh = 1.0f / (sqrtf(1.0f - pv) + 1e-8f);
        const float ch = (zh - 1.0f) / (pv + 1e-9f);
        const float zt = 1.0f / (sqrtf(1.0f - qv) + 1e-8f);
        const float ct = (zt - 1.0f) / (qv + 1e-9f);

        // head rotation: x <- x H0 H1 ... H30 (grouped by 4, exact)
        float x = act ? hsld[1 + k] : 0.0f;
        const float h0 = hsld[0];
        #pragma unroll
        for (int g2 = 0; g2 < 8; ++g2) {
            const int base = g2 * 4;
            const float w0 = wrow[base + 0][k];
            const float w1 = wrow[base + 1][k];
            const float w2 = wrow[base + 2][k];
            const float w3 = wrow[base + 3][k];
            float p0 = reduce32(x * w0);
            float p1 = reduce32(x * w1);
            float p2 = reduce32(x * w2);
            float p3 = reduce32(x * w3);
            const float* cg = cd[0][g2];
            const float a0 = inv2n[base + 0] * p0;
            const float a1 = inv2n[base + 1] * fmaf(-a0, cg[0], p1);
            const float a2 = inv2n[base + 2] * (p2 - fmaf(a0, cg[1], a1 * cg[3]));
            const float a3 = inv2n[base + 3] * (p3 - fmaf(a0, cg[2], fmaf(a1, cg[4], a2 * cg[5])));
            x = x - (fmaf(a0, w0, a1 * w1) + fmaf(a2, w2, a3 * w3));
        }

        // head boost (reference formulas, same eps)
        const float pd = reduce32(x * roh);
        const float th  = fmaf(roh, ch * pd - zh * h0, x);   // spatial comp k
        const float th0 = zh * (h0 - pd);

        // y = 2 * B_tail * (G th)
        const float qd = reduce32(rot * th);
        const float qb = reduce32(th * th);
        float y = 2.0f * fmaf(fmaf(zt, th0, ct * qd), rot, th);
        const float y0 = 2.0f * zt * (-th0 - qd);

        // tail rotation: w_sp = H0 (H1 (... (H30 y_sp))) — groups descending,
        // descending within group (H3 first), exact recurrence.
        #pragma unroll
        for (int g2 = 7; g2 >= 0; --g2) {
            const int base = 32 + g2 * 4;
            const float w0 = wrow[base + 0][k];
            const float w1 = wrow[base + 1][k];
            const float w2 = wrow[base + 2][k];
            const float w3 = wrow[base + 3][k];
            float p0 = reduce32(y * w0);
            float p1 = reduce32(y * w1);
            float p2 = reduce32(y * w2);
            float p3 = reduce32(y * w3);
            const float* cg = cd[1][g2];
            const float b3 = inv2n[base + 3] * p3;
            const float b2 = inv2n[base + 2] * fmaf(-b3, cg[5], p2);
            const float b1 = inv2n[base + 1] * (p1 - fmaf(b3, cg[4], b2 * cg[3]));
            const float b0 = inv2n[base + 0] * (p0 - fmaf(b3, cg[2], fmaf(b2, cg[1], b1 * cg[0])));
            y = y - (fmaf(b0, w0, b1 * w1) + fmaf(b2, w2, b3 * w3));
        }

        if (tid < 32) {
            if (act) wl[1 + k] = y;
            else     wl[0] = y0;            // lane 31
        }
        if (tid == 0) {
            const float beta = qb - th0 * th0;
            wl[32] = MARGIN - beta + tanhf(bias_head[ub]);
        }
    }
    __syncthreads();   // drains the in-flight gathers too

    // ---- phase 3: score from pre-fetched registers ----
    float dotw = 0.0f, qsum = 0.0f;
    const float t0 = e0.x;
#define ACC(EV, WI)                                                       \
    {                                                                     \
        const float4 wq = *reinterpret_cast<const float4*>(&wl[4 * WI]);  \
        dotw = fmaf(EV.x, wq.x, dotw); dotw = fmaf(EV.y, wq.y, dotw);     \
        dotw = fmaf(EV.z, wq.z, dotw); dotw = fmaf(EV.w, wq.w, dotw);     \
        qsum = fmaf(EV.x, EV.x, qsum); qsum = fmaf(EV.y, EV.y, qsum);     \
        qsum = fmaf(EV.z, EV.z, qsum); qsum = fmaf(EV.w, EV.w, qsum);     \
    }
    ACC(e0, 0) ACC(e1, 1) ACC(e2, 2) ACC(e3, 3)
    ACC(e4, 4) ACC(e5, 5) ACC(e6, 6) ACC(e7, 7)
#undef ACC

    out[(size_t)b * 256 + tid] = wl[32] + dotw - qsum + 2.0f * t0 * t0 + tanhf(btl);
}

extern "C" void kernel_launch(void* const* d_in, const int* in_sizes, int n_in,
                              void* d_out, int out_size, void* d_ws, size_t ws_size,
                              hipStream_t stream) {
    (void)n_in; (void)out_size; (void)d_ws; (void)ws_size;
    const int B = in_sizes[0];   // 1024
    fused_kernel<<<B, 256, 0, stream>>>(
        (const int*)d_in[0], (const int*)d_in[1], (const int*)d_in[2],
        (const float*)d_in[3], (const float*)d_in[4], (const float*)d_in[5],
        (const float*)d_in[6], (const float*)d_in[7],
        (const float*)d_in[8], (const float*)d_in[9],
        (float*)d_out);
}